// Round 2
// baseline (57.902 us; speedup 1.0000x reference)
//
#include <hip/hip_runtime.h>

// DigitCaps (collapsed routing, faithful-to-source reference):
//   s[o,d] = (1/512) * sum_n sum_k W[n,o,d,k] * x[n,k]
//   v[o,d] = (s^2/(1+s^2)) * s/(sqrt(s^2+1e-7)+1e-7)   (squash axis is size 1 => elementwise)
//
// All float32 (per reference dtypes). x: [512][8], W: [512][10][16][8], out: [10][16].
// 655K MACs, 2.6 MB traffic -> launch/latency-bound. Single kernel, single pass.

#define N_IN  512
#define N_OUT 10
#define D_OUT 16
#define D_IN  8

__global__ __launch_bounds__(256) void digitcaps_kernel(
    const float* __restrict__ x,   // [512][8]
    const float* __restrict__ W,   // [512][10][16][8]
    float* __restrict__ out)       // [10][16] flat: o*16 + d
{
    const int od = blockIdx.x;           // 0..159 => one (o,d) per block
    const int o  = od >> 4;
    const int d  = od & 15;
    const int t  = threadIdx.x;          // 0..255

    float acc = 0.0f;

    #pragma unroll
    for (int rep = 0; rep < 2; ++rep) {
        const int n = t + rep * 256;     // n = 0..511
        // W[n][o][d][0..7]: 8 contiguous floats, 32B-aligned
        const float4* wp = reinterpret_cast<const float4*>(
            W + ((size_t)(n * N_OUT + o) * D_OUT + d) * D_IN);
        // x[n][0..7]
        const float4* xp = reinterpret_cast<const float4*>(x + (size_t)n * D_IN);
        const float4 w0 = wp[0], w1 = wp[1];
        const float4 x0 = xp[0], x1 = xp[1];
        acc += w0.x * x0.x + w0.y * x0.y + w0.z * x0.z + w0.w * x0.w
             + w1.x * x1.x + w1.y * x1.y + w1.z * x1.z + w1.w * x1.w;
    }

    // wave-64 butterfly reduction
    #pragma unroll
    for (int off = 32; off > 0; off >>= 1)
        acc += __shfl_down(acc, off, 64);

    // cross-wave (4 waves) reduction through LDS
    __shared__ float wsum[4];
    const int wave = t >> 6;
    const int lane = t & 63;
    if (lane == 0) wsum[wave] = acc;
    __syncthreads();

    if (t == 0) {
        const float s    = (wsum[0] + wsum[1] + wsum[2] + wsum[3]) * (1.0f / (float)N_IN);
        const float sq   = s * s;
        const float norm = s / (sqrtf(sq + 1e-7f) + 1e-7f);
        out[od] = (sq / (1.0f + sq)) * norm;
    }
}

extern "C" void kernel_launch(void* const* d_in, const int* in_sizes, int n_in,
                              void* d_out, int out_size, void* d_ws, size_t ws_size,
                              hipStream_t stream) {
    const float* x = (const float*)d_in[0];   // 4096 floats
    const float* W = (const float*)d_in[1];   // 655360 floats
    float* out = (float*)d_out;               // 160 floats
    digitcaps_kernel<<<dim3(N_OUT * D_OUT), dim3(256), 0, stream>>>(x, W, out);
}

// Round 3
// 57.332 us; speedup vs baseline: 1.0099x; 1.0099x over previous
//
#include <hip/hip_runtime.h>

// DigitCaps (collapsed routing, faithful-to-source reference):
//   s[o,d] = (1/512) * sum_n sum_k W[n,o,d,k] * x[n,k]
//   v[o,d] = (s^2/(1+s^2)) * s/(sqrt(s^2+1e-7)+1e-7)    (squash axis size 1 => elementwise)
//
// float32. x: [512][8], W: [512][10][16][8], out: [10][16].
//
// Layout-aware version: block b = (o, d-group-of-4). Lanes t..t+3 read 4
// consecutive 32B W segments => one full 128B cache line per 4 lanes
// (fully coalesced; W read exactly once). 8 independent load pairs per
// thread, one waitcnt. 40 blocks x 256 threads.

#define N_IN  512
#define N_OUT 10
#define D_OUT 16
#define D_IN  8

__global__ __launch_bounds__(256) void digitcaps_kernel(
    const float* __restrict__ x,   // [512][8]
    const float* __restrict__ W,   // [512][10][16][8]
    float* __restrict__ out)       // [10][16] flat: o*16 + d
{
    const int b  = blockIdx.x;       // 0..39
    const int o  = b >> 2;           // 0..9
    const int dg = b & 3;            // d-group: d = dg*4 + (t&3)
    const int t  = threadIdx.x;      // 0..255
    const int dl = t & 3;            // d_local
    const int d  = dg * 4 + dl;
    const int nb = t >> 2;           // base n (0..63)

    float acc = 0.0f;

    #pragma unroll
    for (int i = 0; i < 8; ++i) {
        const int n = nb + 64 * i;   // n = 0..511
        // W[n][o][d][0..7]: 8 contiguous floats; lanes t..t+3 cover 128B line
        const float4* wp = reinterpret_cast<const float4*>(
            W + ((size_t)(n * N_OUT + o) * D_OUT + d) * D_IN);
        const float4* xp = reinterpret_cast<const float4*>(x + (size_t)n * D_IN);
        const float4 w0 = wp[0], w1 = wp[1];
        const float4 x0 = xp[0], x1 = xp[1];
        acc += w0.x * x0.x + w0.y * x0.y + w0.z * x0.z + w0.w * x0.w
             + w1.x * x1.x + w1.y * x1.y + w1.z * x1.z + w1.w * x1.w;
    }

    // Butterfly over the 16 lanes sharing d_local within this wave
    // (lanes differing in bits 2..5 have the same t&3).
    #pragma unroll
    for (int m = 4; m <= 32; m <<= 1)
        acc += __shfl_xor(acc, m, 64);

    // Cross-wave (4 waves) reduction: wsum[wave][d_local]
    __shared__ float wsum[4 * 4];
    const int wave = t >> 6;
    const int lane = t & 63;
    if (lane < 4) wsum[wave * 4 + lane] = acc;
    __syncthreads();

    if (t < 4) {
        const float s    = (wsum[0 + t] + wsum[4 + t] + wsum[8 + t] + wsum[12 + t])
                           * (1.0f / (float)N_IN);
        const float sq   = s * s;
        const float norm = s / (sqrtf(sq + 1e-7f) + 1e-7f);
        out[o * D_OUT + dg * 4 + t] = (sq / (1.0f + sq)) * norm;
    }
}

extern "C" void kernel_launch(void* const* d_in, const int* in_sizes, int n_in,
                              void* d_out, int out_size, void* d_ws, size_t ws_size,
                              hipStream_t stream) {
    const float* x = (const float*)d_in[0];   // 4096 floats
    const float* W = (const float*)d_in[1];   // 655360 floats
    float* out = (float*)d_out;               // 160 floats
    digitcaps_kernel<<<dim3(N_OUT * 4), dim3(256), 0, stream>>>(x, W, out);
}